// Round 8
// baseline (1191.261 us; speedup 1.0000x reference)
//
#include <hip/hip_runtime.h>
#include <hip/hip_fp16.h>

#define BS 256
#define BSHIFT 8                // 256 nodes per bucket
#define BNODES (1 << BSHIFT)
#define NBKT 512                // bucket table size (>= ceil(131072/256)); n <= 2^17 req'd
#define CAP 6144                // edge capacity per bucket (mean 4092 at E=1.6M, +32 sigma)
#define CHUNK 4096              // edges per block for scatter (16/thread)
// packed edge word: src in bits [0,17), local dst (li) in bits [17,25)

typedef _Float16 f16x8 __attribute__((ext_vector_type(8)));
typedef float f32x4 __attribute__((ext_vector_type(4)));

// ---------------- bucketed edge binning (fixed-capacity, no scan) ----------------

__global__ __launch_bounds__(BS) void k_scatter(const int* __restrict__ src,
                                                const int* __restrict__ dst,
                                                int* __restrict__ gcursor,
                                                int* __restrict__ binned, int E) {
    __shared__ int h[NBKT];
    __shared__ int base[NBKT];
    int t = threadIdx.x;
    h[t] = 0; h[t + BS] = 0;
    __syncthreads();
    int cbase = blockIdx.x * CHUNK;
    int sv[CHUNK / BS], dv[CHUNK / BS], rv[CHUNK / BS];
#pragma unroll
    for (int j = 0; j < CHUNK / BS; ++j) {
        int e = cbase + j * BS + t;
        rv[j] = -1;
        if (e < E) {
            sv[j] = src[e];
            dv[j] = dst[e];
            rv[j] = atomicAdd(&h[dv[j] >> BSHIFT], 1);
        }
    }
    __syncthreads();
    for (int i = t; i < NBKT; i += BS)
        base[i] = h[i] ? atomicAdd(&gcursor[i], h[i]) : 0;
    __syncthreads();
#pragma unroll
    for (int j = 0; j < CHUNK / BS; ++j) {
        if (rv[j] >= 0) {
            int b = dv[j] >> BSHIFT;
            binned[(size_t)b * CAP + base[b] + rv[j]] =
                sv[j] | ((dv[j] & (BNODES - 1)) << 17);
        }
    }
}

// one block per bucket: degree histogram -> dinv (deg includes +1 self-loop)
__global__ __launch_bounds__(BS) void k_deginv(const int* __restrict__ binned,
                                               const int* __restrict__ cnts,
                                               float* __restrict__ dinv, int n) {
    __shared__ int dg[BNODES];
    int t = threadIdx.x, bkt = blockIdx.x;
    int node0 = bkt << BSHIFT;
    int nn = min(BNODES, n - node0);
    dg[t] = 0;
    __syncthreads();
    int cnt = cnts[bkt];
    const int* eb = binned + (size_t)bkt * CAP;
    for (int e = t; e < cnt; e += BS) atomicAdd(&dg[eb[e] >> 17], 1);
    __syncthreads();
    if (t < nn) dinv[node0 + t] = rsqrtf((float)(dg[t] + 1));
}

// ---------------- MFMA GEMM: H[i][c] = fp16(dinv[i] * sum_k act(X[i][k]) * W[k][c]) ----
// A fragments loaded DIRECTLY global->VGPR; only W^T staged in LDS, one barrier.
// Layouts (verified r5): A[m=lane&15][k=quad*8+j], B^T[n=lane&15][k=quad*8+j],
// D row=quad*4+reg col=lane&15.

template <int K, int COLS, bool FUSE, bool IN_HALF>
__global__ __launch_bounds__(BS, 4) void k_mgemm(const void* __restrict__ Xv,
                                                 const float* __restrict__ W,
                                                 const float* __restrict__ bias,
                                                 const float* __restrict__ dscale,
                                                 __half* __restrict__ H, int n) {
    constexpr int KC = K / 8;                           // 16B chunks per row
    constexpr int SWZ = (KC - 1) < 15 ? (KC - 1) : 15;  // 15 (K=128) / 7 (K=64)
    constexpr int NT = COLS / 16;                       // n-tiles per wave
    __shared__ __align__(16) _Float16 sB[COLS * K];
    int tid = threadIdx.x;

    for (int idx = tid; idx < COLS * KC; idx += BS) {
        int c = idx / KC, k8 = idx % KC;
        f16x8 v;
#pragma unroll
        for (int j = 0; j < 8; ++j) v[j] = (_Float16)W[(k8 * 8 + j) * COLS + c];
        *(f16x8*)&sB[c * K + ((k8 ^ (c & SWZ)) * 8)] = v;
    }
    __syncthreads();

    int w = tid >> 6, lane = tid & 63;
    int lm = lane & 15, q = lane >> 4;
    int row_m0 = blockIdx.x * 128 + w * 32;

    f32x4 acc[2][NT];
#pragma unroll
    for (int tm = 0; tm < 2; ++tm)
#pragma unroll
        for (int tn = 0; tn < NT; ++tn) acc[tm][tn] = (f32x4){0.f, 0.f, 0.f, 0.f};

#pragma unroll
    for (int kk = 0; kk < K / 32; ++kk) {
        int k0 = kk * 32 + q * 8;
        f16x8 af[2], bf[NT];
#pragma unroll
        for (int tm = 0; tm < 2; ++tm) {
            int row = row_m0 + tm * 16 + lm;
            int rl = row < n ? row : (n - 1);  // clamp: in-bounds, values unused
            if (IN_HALF) {
                f16x8 raw = *(const f16x8*)((const _Float16*)Xv + (size_t)rl * K + k0);
                if (FUSE) {
                    const float4* bp = (const float4*)(bias + k0);
                    float4 ba = bp[0], bb = bp[1];
                    float f[8] = {(float)raw[0], (float)raw[1], (float)raw[2], (float)raw[3],
                                  (float)raw[4], (float)raw[5], (float)raw[6], (float)raw[7]};
                    f[0] = fmaxf(f[0] + ba.x, 0.f); f[1] = fmaxf(f[1] + ba.y, 0.f);
                    f[2] = fmaxf(f[2] + ba.z, 0.f); f[3] = fmaxf(f[3] + ba.w, 0.f);
                    f[4] = fmaxf(f[4] + bb.x, 0.f); f[5] = fmaxf(f[5] + bb.y, 0.f);
                    f[6] = fmaxf(f[6] + bb.z, 0.f); f[7] = fmaxf(f[7] + bb.w, 0.f);
#pragma unroll
                    for (int j = 0; j < 8; ++j) raw[j] = (_Float16)f[j];
                }
                af[tm] = raw;
            } else {
                const float4* xp = (const float4*)Xv + ((size_t)rl * K + k0) / 4;
                float4 a = xp[0], b = xp[1];
                f16x8 v;
                v[0] = (_Float16)a.x; v[1] = (_Float16)a.y;
                v[2] = (_Float16)a.z; v[3] = (_Float16)a.w;
                v[4] = (_Float16)b.x; v[5] = (_Float16)b.y;
                v[6] = (_Float16)b.z; v[7] = (_Float16)b.w;
                af[tm] = v;
            }
        }
#pragma unroll
        for (int tn = 0; tn < NT; ++tn) {
            int c = tn * 16 + lm;
            bf[tn] = *(const f16x8*)&sB[c * K + (((kk * 4 + q) ^ (c & SWZ)) * 8)];
        }
#pragma unroll
        for (int tm = 0; tm < 2; ++tm)
#pragma unroll
            for (int tn = 0; tn < NT; ++tn)
                acc[tm][tn] = __builtin_amdgcn_mfma_f32_16x16x32_f16(af[tm], bf[tn],
                                                                     acc[tm][tn], 0, 0, 0);
    }

#pragma unroll
    for (int tm = 0; tm < 2; ++tm) {
#pragma unroll
        for (int r = 0; r < 4; ++r) {
            int row = row_m0 + tm * 16 + q * 4 + r;
            if (row < n) {
                float dv = dscale[row];
#pragma unroll
                for (int tn = 0; tn < NT; ++tn) {
                    int col = tn * 16 + lm;
                    H[(size_t)row * COLS + col] = __float2half_rn(acc[tm][tn][r] * dv);
                }
            }
        }
    }
}

// ---------------- Aggregation: bucket-local LDS scatter (no CSR) ----------------
// One block per 256-node bucket; fp32 LDS accumulator initialized with the bucket's
// own h rows (= self-loop term, h pre-scaled by dinv). Edges streamed contiguously;
// 16 lanes/edge broadcast-load the packed word, gather 128B of h[src], ds_add_f32
// with per-group j-rotation (groups mod 4 -> disjoint bank quarters, conflict-free).

__global__ __launch_bounds__(BS, 2) void k_sagg64(const __half* __restrict__ h,
                                                  const int* __restrict__ binned,
                                                  const int* __restrict__ cnts,
                                                  const float* __restrict__ dinv,
                                                  __half* __restrict__ out, int n) {
    __shared__ float acc[BNODES * 64];  // 64 KB
    int t = threadIdx.x, bkt = blockIdx.x;
    int node0 = bkt << BSHIFT;
    int nn = min(BNODES, n - node0);
    // init with self rows (fp16 -> fp32)
    for (int idx = t; idx < nn * 8; idx += BS) {
        int r = idx >> 3, c8 = idx & 7;
        f16x8 v = *(const f16x8*)((const _Float16*)h + (size_t)(node0 + r) * 64 + c8 * 8);
        float* a = acc + r * 64 + c8 * 8;
#pragma unroll
        for (int j = 0; j < 8; ++j) a[j] = (float)v[j];
    }
    __syncthreads();
    int cnt = cnts[bkt];
    const int* eb = binned + (size_t)bkt * CAP;
    int grp = t >> 4, fq = t & 15, g3 = grp & 3;
    for (int e0 = 0; e0 < cnt; e0 += 32) {
        int eA = e0 + grp, eB = e0 + 16 + grp;
        int wA = (eA < cnt) ? eb[eA] : -1;
        int wB = (eB < cnt) ? eb[eB] : -1;
        float2 rA, rB;
        if (wA >= 0) rA = *((const float2*)(h + (size_t)(wA & 0x1FFFF) * 64) + fq);
        if (wB >= 0) rB = *((const float2*)(h + (size_t)(wB & 0x1FFFF) * 64) + fq);
        if (wA >= 0) {
            __half2 u0 = ((const __half2*)&rA)[0], u1 = ((const __half2*)&rA)[1];
            float2 p0 = __half22float2(u0), p1 = __half22float2(u1);
            float f[4] = {p0.x, p0.y, p1.x, p1.y};
            float* a = acc + (wA >> 17) * 64 + fq * 4;
#pragma unroll
            for (int j = 0; j < 4; ++j) { int jj = (j + g3) & 3; atomicAdd(&a[jj], f[jj]); }
        }
        if (wB >= 0) {
            __half2 u0 = ((const __half2*)&rB)[0], u1 = ((const __half2*)&rB)[1];
            float2 p0 = __half22float2(u0), p1 = __half22float2(u1);
            float f[4] = {p0.x, p0.y, p1.x, p1.y};
            float* a = acc + (wB >> 17) * 64 + fq * 4;
#pragma unroll
            for (int j = 0; j < 4; ++j) { int jj = (j + g3) & 3; atomicAdd(&a[jj], f[jj]); }
        }
    }
    __syncthreads();
    for (int idx = t; idx < nn * 8; idx += BS) {
        int r = idx >> 3, c8 = idx & 7;
        float dv = dinv[node0 + r];
        const float* a = acc + r * 64 + c8 * 8;
        f16x8 v;
#pragma unroll
        for (int j = 0; j < 8; ++j) v[j] = (_Float16)(a[j] * dv);
        *(f16x8*)((_Float16*)out + (size_t)(node0 + r) * 64 + c8 * 8) = v;
    }
}

// 32-feature variant: 8 lanes/edge, fp32 out + bias (final layer).
__global__ __launch_bounds__(BS, 4) void k_sagg32(const __half* __restrict__ h,
                                                  const int* __restrict__ binned,
                                                  const int* __restrict__ cnts,
                                                  const float* __restrict__ dinv,
                                                  const float* __restrict__ bias,
                                                  float* __restrict__ out, int n) {
    __shared__ float acc[BNODES * 32];  // 32 KB
    int t = threadIdx.x, bkt = blockIdx.x;
    int node0 = bkt << BSHIFT;
    int nn = min(BNODES, n - node0);
    for (int idx = t; idx < nn * 4; idx += BS) {
        int r = idx >> 2, c8 = idx & 3;
        f16x8 v = *(const f16x8*)((const _Float16*)h + (size_t)(node0 + r) * 32 + c8 * 8);
        float* a = acc + r * 32 + c8 * 8;
#pragma unroll
        for (int j = 0; j < 8; ++j) a[j] = (float)v[j];
    }
    __syncthreads();
    int cnt = cnts[bkt];
    const int* eb = binned + (size_t)bkt * CAP;
    int grp = t >> 3, fq = t & 7, g3 = grp & 3;
    for (int e0 = 0; e0 < cnt; e0 += 64) {
        int eA = e0 + grp, eB = e0 + 32 + grp;
        int wA = (eA < cnt) ? eb[eA] : -1;
        int wB = (eB < cnt) ? eb[eB] : -1;
        float2 rA, rB;
        if (wA >= 0) rA = *((const float2*)(h + (size_t)(wA & 0x1FFFF) * 32) + fq);
        if (wB >= 0) rB = *((const float2*)(h + (size_t)(wB & 0x1FFFF) * 32) + fq);
        if (wA >= 0) {
            __half2 u0 = ((const __half2*)&rA)[0], u1 = ((const __half2*)&rA)[1];
            float2 p0 = __half22float2(u0), p1 = __half22float2(u1);
            float f[4] = {p0.x, p0.y, p1.x, p1.y};
            float* a = acc + (wA >> 17) * 32 + fq * 4;
#pragma unroll
            for (int j = 0; j < 4; ++j) { int jj = (j + g3) & 3; atomicAdd(&a[jj], f[jj]); }
        }
        if (wB >= 0) {
            __half2 u0 = ((const __half2*)&rB)[0], u1 = ((const __half2*)&rB)[1];
            float2 p0 = __half22float2(u0), p1 = __half22float2(u1);
            float f[4] = {p0.x, p0.y, p1.x, p1.y};
            float* a = acc + (wB >> 17) * 32 + fq * 4;
#pragma unroll
            for (int j = 0; j < 4; ++j) { int jj = (j + g3) & 3; atomicAdd(&a[jj], f[jj]); }
        }
    }
    __syncthreads();
    for (int idx = t; idx < nn * 8; idx += BS) {
        int r = idx >> 3, c4 = idx & 7;
        float dv = dinv[node0 + r];
        f32x4 a = *(const f32x4*)(acc + r * 32 + c4 * 4);
        float4 bv = ((const float4*)bias)[c4];
        float4 o = make_float4(a[0] * dv + bv.x, a[1] * dv + bv.y,
                               a[2] * dv + bv.z, a[3] * dv + bv.w);
        ((float4*)(out + (size_t)(node0 + r) * 32))[c4] = o;
    }
}

// ---------------- launch ----------------

extern "C" void kernel_launch(void* const* d_in, const int* in_sizes, int n_in,
                              void* d_out, int out_size, void* d_ws, size_t ws_size,
                              hipStream_t stream) {
    const float* x  = (const float*)d_in[0];
    const int* eidx = (const int*)d_in[1];
    const float* W1 = (const float*)d_in[2];
    const float* b1 = (const float*)d_in[3];
    const float* W2 = (const float*)d_in[4];
    const float* b2 = (const float*)d_in[5];
    float* out = (float*)d_out;

    int n = in_sizes[0] / 128;
    int E = in_sizes[1] / 2;
    const int* srcA = eidx;
    const int* dstA = eidx + E;

    char* p = (char*)d_ws;
    auto alloc = [&](size_t bytes) {
        char* q = p;
        p += (bytes + 255) & ~(size_t)255;
        return q;
    };
    float*  dinv    = (float*)alloc((size_t)n * 4);
    int*    gcursor = (int*)alloc(NBKT * 4);
    int*    binned  = (int*)alloc((size_t)NBKT * CAP * 4);
    __half* h1      = (__half*)alloc((size_t)n * 64 * 2);
    __half* g1      = (__half*)alloc((size_t)n * 64 * 2);
    __half* h2      = (__half*)alloc((size_t)n * 32 * 2);

    int nchunks  = (E + CHUNK - 1) / CHUNK;           // 391
    int nbuckets = (n + BNODES - 1) / BNODES;         // 391 (<= NBKT)
    int nblk     = (n + 127) / 128;                   // 782 MFMA-GEMM tiles

    hipMemsetAsync(gcursor, 0, NBKT * 4, stream);
    k_scatter<<<nchunks, BS, 0, stream>>>(srcA, dstA, gcursor, binned, E);
    k_deginv<<<nbuckets, BS, 0, stream>>>(binned, gcursor, dinv, n);

    // layer 1: h1 = dinv .* (x @ W1)  [fp16 MFMA]; g1 = dinv .* (A h1)  [LDS scatter]
    k_mgemm<128, 64, false, false><<<nblk, BS, 0, stream>>>(x, W1, nullptr, dinv, h1, n);
    k_sagg64<<<nbuckets, BS, 0, stream>>>(h1, binned, gcursor, dinv, g1, n);

    // layer 2: h2 = dinv .* (relu(g1 + b1) @ W2); out = dinv .* (A h2) + b2  [fp32]
    k_mgemm<64, 32, true, true><<<nblk, BS, 0, stream>>>(g1, W2, b1, dinv, h2, n);
    k_sagg32<<<nbuckets, BS, 0, stream>>>(h2, binned, gcursor, dinv, b2, out, n);
}

// Round 9
// 253.823 us; speedup vs baseline: 4.6933x; 4.6933x over previous
//
#include <hip/hip_runtime.h>
#include <hip/hip_fp16.h>

#define BS 256
#define BSHIFT 9                // 512 nodes per bucket
#define BNODES (1 << BSHIFT)
#define NBKT 256                // bucket table size (>= ceil(100000/512)=196); n <= 2^17
#define CAP 12288               // edge capacity per bucket (mean 8163 at E=1.6M, +45 sigma)
#define CHUNK 4096              // edges per block for scatter (16/thread)
// packed edge word: src in bits [0,17), local dst (li) in bits [17,26)

typedef _Float16 f16x8 __attribute__((ext_vector_type(8)));
typedef float f32x4 __attribute__((ext_vector_type(4)));

// ---------------- bucketed edge binning (fixed-capacity, no global scan) ----------------

__global__ __launch_bounds__(BS) void k_scatter(const int* __restrict__ src,
                                                const int* __restrict__ dst,
                                                int* __restrict__ gcursor,
                                                int* __restrict__ binned, int E) {
    __shared__ int h[NBKT];
    __shared__ int base[NBKT];
    int t = threadIdx.x;
    h[t] = 0;
    __syncthreads();
    int cbase = blockIdx.x * CHUNK;
    int sv[CHUNK / BS], dv[CHUNK / BS], rv[CHUNK / BS];
#pragma unroll
    for (int j = 0; j < CHUNK / BS; ++j) {
        int e = cbase + j * BS + t;
        rv[j] = -1;
        if (e < E) {
            sv[j] = src[e];
            dv[j] = dst[e];
            rv[j] = atomicAdd(&h[dv[j] >> BSHIFT], 1);
        }
    }
    __syncthreads();
    base[t] = h[t] ? atomicAdd(&gcursor[t], h[t]) : 0;
    __syncthreads();
#pragma unroll
    for (int j = 0; j < CHUNK / BS; ++j) {
        if (rv[j] >= 0) {
            int b = dv[j] >> BSHIFT;
            binned[(size_t)b * CAP + base[b] + rv[j]] =
                sv[j] | ((dv[j] & (BNODES - 1)) << 17);
        }
    }
}

// one block per bucket: degree histogram -> LDS scan -> rowptr2/dinv -> CSR fill.
// CSR is bucket-relative: bucket b owns csr[b*(CAP+BNODES) ...); per-node (start,end)
// stored as int2 so gaps between buckets are harmless. Self-loop at slot 0.
__global__ __launch_bounds__(BS) void k_build(const int* __restrict__ binned,
                                              const int* __restrict__ cnts,
                                              int2* __restrict__ rowptr2,
                                              float* __restrict__ dinv,
                                              int* __restrict__ csr, int n) {
    __shared__ int h[BNODES];
    __shared__ int rp[BNODES];
    __shared__ int cur[BNODES];
    __shared__ int ws[4];
    int t = threadIdx.x;
    int bkt = blockIdx.x;
    int node0 = bkt << BSHIFT;
    int nn = min(BNODES, n - node0);
#pragma unroll
    for (int i = t; i < BNODES; i += BS) h[i] = 0;
    __syncthreads();
    int cnt = cnts[bkt];
    const int* eb = binned + (size_t)bkt * CAP;
    for (int e = t; e < cnt; e += BS) atomicAdd(&h[eb[e] >> 17], 1);
    __syncthreads();
    // exclusive scan of h[0..512): each thread owns 2 elements
    int i0 = 2 * t;
    int v0 = h[i0], v1 = h[i0 + 1];
    int pair = v0 + v1;
    int lane = t & 63, w = t >> 6;
    int incl = pair;
#pragma unroll
    for (int off = 1; off < 64; off <<= 1) {
        int u = __shfl_up(incl, off);
        if (lane >= off) incl += u;
    }
    if (lane == 63) ws[w] = incl;
    __syncthreads();
    int woff = 0;
    for (int q = 0; q < w; ++q) woff += ws[q];
    int excl = woff + incl - pair;  // bucket-local edges before node i0
    int cb = bkt * (CAP + BNODES);
    int r0 = cb + excl + i0;        // + i0 self-loops of earlier nodes
    int r1 = r0 + v0 + 1;
    rp[i0] = r0; rp[i0 + 1] = r1;
    cur[i0] = 1; cur[i0 + 1] = 1;   // slot 0 = self-loop
    if (i0 < nn) {
        rowptr2[node0 + i0] = make_int2(r0, r1);
        dinv[node0 + i0] = rsqrtf((float)(v0 + 1));
        csr[r0] = node0 + i0;
    }
    if (i0 + 1 < nn) {
        rowptr2[node0 + i0 + 1] = make_int2(r1, r1 + v1 + 1);
        dinv[node0 + i0 + 1] = rsqrtf((float)(v1 + 1));
        csr[r1] = node0 + i0 + 1;
    }
    __syncthreads();
    for (int e = t; e < cnt; e += BS) {
        int p = eb[e];
        int li = p >> 17;
        int r = atomicAdd(&cur[li], 1);
        csr[rp[li] + r] = p & 0x1FFFF;
    }
}

// ---------------- MFMA GEMM: H[i][c] = fp16(dinv[i] * sum_k act(X[i][k]) * W[k][c]) ----
// A fragments loaded DIRECTLY global->VGPR; only W^T staged in LDS, one barrier.
// Layouts (verified r5): A[m=lane&15][k=quad*8+j], B^T[n=lane&15][k=quad*8+j],
// D row=quad*4+reg col=lane&15.

template <int K, int COLS, bool FUSE, bool IN_HALF>
__global__ __launch_bounds__(BS, 4) void k_mgemm(const void* __restrict__ Xv,
                                                 const float* __restrict__ W,
                                                 const float* __restrict__ bias,
                                                 const float* __restrict__ dscale,
                                                 __half* __restrict__ H, int n) {
    constexpr int KC = K / 8;                           // 16B chunks per row
    constexpr int SWZ = (KC - 1) < 15 ? (KC - 1) : 15;  // 15 (K=128) / 7 (K=64)
    constexpr int NT = COLS / 16;                       // n-tiles per wave
    __shared__ __align__(16) _Float16 sB[COLS * K];
    int tid = threadIdx.x;

    for (int idx = tid; idx < COLS * KC; idx += BS) {
        int c = idx / KC, k8 = idx % KC;
        f16x8 v;
#pragma unroll
        for (int j = 0; j < 8; ++j) v[j] = (_Float16)W[(k8 * 8 + j) * COLS + c];
        *(f16x8*)&sB[c * K + ((k8 ^ (c & SWZ)) * 8)] = v;
    }
    __syncthreads();

    int w = tid >> 6, lane = tid & 63;
    int lm = lane & 15, q = lane >> 4;
    int row_m0 = blockIdx.x * 128 + w * 32;

    f32x4 acc[2][NT];
#pragma unroll
    for (int tm = 0; tm < 2; ++tm)
#pragma unroll
        for (int tn = 0; tn < NT; ++tn) acc[tm][tn] = (f32x4){0.f, 0.f, 0.f, 0.f};

#pragma unroll
    for (int kk = 0; kk < K / 32; ++kk) {
        int k0 = kk * 32 + q * 8;
        f16x8 af[2], bf[NT];
#pragma unroll
        for (int tm = 0; tm < 2; ++tm) {
            int row = row_m0 + tm * 16 + lm;
            int rl = row < n ? row : (n - 1);  // clamp: in-bounds, values unused
            if (IN_HALF) {
                f16x8 raw = *(const f16x8*)((const _Float16*)Xv + (size_t)rl * K + k0);
                if (FUSE) {
                    const float4* bp = (const float4*)(bias + k0);
                    float4 ba = bp[0], bb = bp[1];
                    float f[8] = {(float)raw[0], (float)raw[1], (float)raw[2], (float)raw[3],
                                  (float)raw[4], (float)raw[5], (float)raw[6], (float)raw[7]};
                    f[0] = fmaxf(f[0] + ba.x, 0.f); f[1] = fmaxf(f[1] + ba.y, 0.f);
                    f[2] = fmaxf(f[2] + ba.z, 0.f); f[3] = fmaxf(f[3] + ba.w, 0.f);
                    f[4] = fmaxf(f[4] + bb.x, 0.f); f[5] = fmaxf(f[5] + bb.y, 0.f);
                    f[6] = fmaxf(f[6] + bb.z, 0.f); f[7] = fmaxf(f[7] + bb.w, 0.f);
#pragma unroll
                    for (int j = 0; j < 8; ++j) raw[j] = (_Float16)f[j];
                }
                af[tm] = raw;
            } else {
                const float4* xp = (const float4*)Xv + ((size_t)rl * K + k0) / 4;
                float4 a = xp[0], b = xp[1];
                f16x8 v;
                v[0] = (_Float16)a.x; v[1] = (_Float16)a.y;
                v[2] = (_Float16)a.z; v[3] = (_Float16)a.w;
                v[4] = (_Float16)b.x; v[5] = (_Float16)b.y;
                v[6] = (_Float16)b.z; v[7] = (_Float16)b.w;
                af[tm] = v;
            }
        }
#pragma unroll
        for (int tn = 0; tn < NT; ++tn) {
            int c = tn * 16 + lm;
            bf[tn] = *(const f16x8*)&sB[c * K + (((kk * 4 + q) ^ (c & SWZ)) * 8)];
        }
#pragma unroll
        for (int tm = 0; tm < 2; ++tm)
#pragma unroll
            for (int tn = 0; tn < NT; ++tn)
                acc[tm][tn] = __builtin_amdgcn_mfma_f32_16x16x32_f16(af[tm], bf[tn],
                                                                     acc[tm][tn], 0, 0, 0);
    }

#pragma unroll
    for (int tm = 0; tm < 2; ++tm) {
#pragma unroll
        for (int r = 0; r < 4; ++r) {
            int row = row_m0 + tm * 16 + q * 4 + r;
            if (row < n) {
                float dv = dscale[row];
#pragma unroll
                for (int tn = 0; tn < NT; ++tn) {
                    int col = tn * 16 + lm;
                    H[(size_t)row * COLS + col] = __float2half_rn(acc[tm][tn][r] * dv);
                }
            }
        }
    }
}

// ---------------- Aggregation (gather-side, no atomics; h in fp16) ----------------
// Two nodes per wave; per 32-lane half, full 32-edge chunks issue ALL 16 (agg64) /
// 8 (agg32) gathers before accumulating (2x r7's in-flight loads — concurrency was
// still the binding resource at r6->r7).

__device__ __forceinline__ void acc_h4(float2 raw, float& x0, float& x1,
                                       float& x2, float& x3) {
    __half2 u0 = ((const __half2*)&raw)[0], u1 = ((const __half2*)&raw)[1];
    float2 f0 = __half22float2(u0), f1 = __half22float2(u1);
    x0 += f0.x; x1 += f0.y; x2 += f1.x; x3 += f1.y;
}

__global__ __launch_bounds__(BS) void k_agg64(const __half* __restrict__ h,
                                              const int* __restrict__ csr,
                                              const int2* __restrict__ rowptr2,
                                              const float* __restrict__ dinv,
                                              __half* __restrict__ out, int n) {
    int wid = (blockIdx.x * BS + threadIdx.x) >> 6;
    int lane = threadIdx.x & 63;
    int half = lane >> 5, hl = lane & 31;
    int node = wid * 2 + half;
    bool valid = node < n;
    int b = 0, e = 0;
    if (valid) { int2 be = rowptr2[node]; b = be.x; e = be.y; }
    int slot = hl >> 4, fq = hl & 15;  // edge slot 0..1, feature quad 0..15
    float a0 = 0.f, a1 = 0.f, a2 = 0.f, a3 = 0.f;
    float c0 = 0.f, c1 = 0.f, c2 = 0.f, c3 = 0.f;
    int c = b;
    for (; c + 32 <= e; c += 32) {
        int sv = csr[c + hl];
        int s[16];
        float2 r[16];
#pragma unroll
        for (int i = 0; i < 16; ++i) s[i] = __shfl(sv, 2 * i + slot, 32);
#pragma unroll
        for (int i = 0; i < 16; ++i)
            r[i] = *((const float2*)(h + (size_t)s[i] * 64) + fq);
#pragma unroll
        for (int i = 0; i < 16; i += 2) {
            acc_h4(r[i], a0, a1, a2, a3);
            acc_h4(r[i + 1], c0, c1, c2, c3);
        }
    }
    {   // tail (< 32 edges)
        int m = e - c;
        int sv = (hl < m) ? csr[c + hl] : 0;
        for (int j = 0; j < m; j += 2) {
            int js = j + slot;
            int s = __shfl(sv, js < m ? js : 0, 32);
            if (js < m) {
                float2 raw = *((const float2*)(h + (size_t)s * 64) + fq);
                acc_h4(raw, a0, a1, a2, a3);
            }
        }
    }
    a0 += c0; a1 += c1; a2 += c2; a3 += c3;
    a0 += __shfl_down(a0, 16); a1 += __shfl_down(a1, 16);
    a2 += __shfl_down(a2, 16); a3 += __shfl_down(a3, 16);
    if (valid && hl < 16) {
        float dv = dinv[node];
        union { __half2 h2[2]; float2 f2; } pk;
        pk.h2[0] = __floats2half2_rn(a0 * dv, a1 * dv);
        pk.h2[1] = __floats2half2_rn(a2 * dv, a3 * dv);
        *(float2*)(out + (size_t)node * 64 + hl * 4) = pk.f2;
    }
}

// 32 features: two nodes per wave, 8 gathers in flight per half; fp32 out + bias.
__global__ __launch_bounds__(BS) void k_agg32(const __half* __restrict__ h,
                                              const int* __restrict__ csr,
                                              const int2* __restrict__ rowptr2,
                                              const float* __restrict__ dinv,
                                              const float* __restrict__ bias,
                                              float* __restrict__ out, int n) {
    int wid = (blockIdx.x * BS + threadIdx.x) >> 6;
    int lane = threadIdx.x & 63;
    int half = lane >> 5, hl = lane & 31;
    int node = wid * 2 + half;
    bool valid = node < n;
    int b = 0, e = 0;
    if (valid) { int2 be = rowptr2[node]; b = be.x; e = be.y; }
    int slot = hl >> 3, fq = hl & 7;  // edge slot 0..3, feature quad 0..7
    float a0 = 0.f, a1 = 0.f, a2 = 0.f, a3 = 0.f;
    float c0 = 0.f, c1 = 0.f, c2 = 0.f, c3 = 0.f;
    int c = b;
    for (; c + 32 <= e; c += 32) {
        int sv = csr[c + hl];
        int s[8];
        float2 r[8];
#pragma unroll
        for (int i = 0; i < 8; ++i) s[i] = __shfl(sv, 4 * i + slot, 32);
#pragma unroll
        for (int i = 0; i < 8; ++i)
            r[i] = *((const float2*)(h + (size_t)s[i] * 32) + fq);
#pragma unroll
        for (int i = 0; i < 8; i += 2) {
            acc_h4(r[i], a0, a1, a2, a3);
            acc_h4(r[i + 1], c0, c1, c2, c3);
        }
    }
    {   // tail
        int m = e - c;
        int sv = (hl < m) ? csr[c + hl] : 0;
        for (int j = 0; j < m; j += 4) {
            int js = j + slot;
            int s = __shfl(sv, js < m ? js : 0, 32);
            if (js < m) {
                float2 raw = *((const float2*)(h + (size_t)s * 32) + fq);
                acc_h4(raw, a0, a1, a2, a3);
            }
        }
    }
    a0 += c0; a1 += c1; a2 += c2; a3 += c3;
    a0 += __shfl_down(a0, 16); a1 += __shfl_down(a1, 16);
    a2 += __shfl_down(a2, 16); a3 += __shfl_down(a3, 16);
    a0 += __shfl_down(a0, 8);  a1 += __shfl_down(a1, 8);
    a2 += __shfl_down(a2, 8);  a3 += __shfl_down(a3, 8);
    if (valid && hl < 8) {
        float dv = dinv[node];
        float4 bv = ((const float4*)bias)[hl];
        float4 o = make_float4(a0 * dv + bv.x, a1 * dv + bv.y,
                               a2 * dv + bv.z, a3 * dv + bv.w);
        ((float4*)(out + (size_t)node * 32))[hl] = o;
    }
}

// ---------------- launch ----------------

extern "C" void kernel_launch(void* const* d_in, const int* in_sizes, int n_in,
                              void* d_out, int out_size, void* d_ws, size_t ws_size,
                              hipStream_t stream) {
    const float* x  = (const float*)d_in[0];
    const int* eidx = (const int*)d_in[1];
    const float* W1 = (const float*)d_in[2];
    const float* b1 = (const float*)d_in[3];
    const float* W2 = (const float*)d_in[4];
    const float* b2 = (const float*)d_in[5];
    float* out = (float*)d_out;

    int n = in_sizes[0] / 128;
    int E = in_sizes[1] / 2;
    const int* srcA = eidx;
    const int* dstA = eidx + E;

    char* p = (char*)d_ws;
    auto alloc = [&](size_t bytes) {
        char* q = p;
        p += (bytes + 255) & ~(size_t)255;
        return q;
    };
    int2*   rowptr2 = (int2*)alloc((size_t)n * 8);
    float*  dinv    = (float*)alloc((size_t)n * 4);
    int*    gcursor = (int*)alloc(NBKT * 4);
    int*    binned  = (int*)alloc((size_t)NBKT * CAP * 4);
    int*    csr     = (int*)alloc((size_t)NBKT * (CAP + BNODES) * 4);
    __half* h1      = (__half*)alloc((size_t)n * 64 * 2);
    __half* g1      = (__half*)alloc((size_t)n * 64 * 2);
    __half* h2      = (__half*)alloc((size_t)n * 32 * 2);

    int nchunks  = (E + CHUNK - 1) / CHUNK;           // 391
    int nbuckets = (n + BNODES - 1) / BNODES;         // 196 (<= NBKT)
    int nblk     = (n + 127) / 128;                   // 782 MFMA-GEMM tiles
    int npairs   = (n + 1) / 2;                       // 2 nodes per wave
    int aggblk   = (int)(((size_t)npairs * 64 + BS - 1) / BS);

    hipMemsetAsync(gcursor, 0, NBKT * 4, stream);
    k_scatter<<<nchunks, BS, 0, stream>>>(srcA, dstA, gcursor, binned, E);
    k_build<<<nbuckets, BS, 0, stream>>>(binned, gcursor, rowptr2, dinv, csr, n);

    // layer 1: h1 = dinv .* (x @ W1)  [fp16 MFMA]; g1 = dinv .* (A-gather h1)
    k_mgemm<128, 64, false, false><<<nblk, BS, 0, stream>>>(x, W1, nullptr, dinv, h1, n);
    k_agg64<<<aggblk, BS, 0, stream>>>(h1, csr, rowptr2, dinv, g1, n);

    // layer 2: h2 = dinv .* (relu(g1 + b1) @ W2); out = dinv .* (A-gather h2) + b2
    k_mgemm<64, 32, true, true><<<nblk, BS, 0, stream>>>(g1, W2, b1, dinv, h2, n);
    k_agg32<<<aggblk, BS, 0, stream>>>(h2, csr, rowptr2, dinv, b2, out, n);
}